// Round 1
// baseline (79.563 us; speedup 1.0000x reference)
//
#include <hip/hip_runtime.h>

#define Hn 28
#define PQ 784     // 28*28
#define NI 128     // B*I

typedef __attribute__((ext_vector_type(8))) short short8v;   // 8 bf16 (4 VGPRs)
typedef __attribute__((ext_vector_type(4))) short short4v;   // 4 bf16 (b64)
typedef __attribute__((ext_vector_type(4))) float float4v;   // MFMA C/D

__device__ __forceinline__ short f2bf(float x) {
    union { float f; unsigned u; } a; a.f = x;
    unsigned r = a.u + 0x7FFF + ((a.u >> 16) & 1);   // RNE
    return (short)(r >> 16);
}

// Single launch, zero workspace. One block per (r,s).
// LDS = 10240+5120+16512+4096+512 = 36480 B -> 4 blocks/CU.
__global__ __launch_bounds__(256, 4) void mono_kernel(
    const float* __restrict__ v,
    const float* __restrict__ W1, const float* __restrict__ b1,
    const float* __restrict__ W2, const float* __restrict__ b2,
    const float* __restrict__ bias, float* __restrict__ out)
{
    __shared__ short sV[NI * 40];       // [ni][p] pad40 bf16  10240 B
    __shared__ short sHt[64 * 40];      // [c][p]  pad40 bf16   5120 B
    __shared__ short sTa[8 * 1032];     // [n8][k=c*16+i] bf16 16512 B
    __shared__ float sRed[4 * 256];     // per-wave partials    4096 B
    __shared__ float sVs[NI];           // row sums              512 B

    const int t = threadIdx.x;
    const int rs = blockIdx.x;
    const int r = rs / Hn;
    const int s = rs - r * Hn;

    // ---- stage V (gather): thread t -> ni = t>>1, p = (t&1)*14 + j.
    // v[ni][p][s] is a 112-B-stride gather (no coalescible direction for fixed s);
    // issue all 14 loads NOW, consume after phase B so latency hides under gelu.
    const int g_ni = t >> 1;
    const int g_p0 = (t & 1) * 14;
    float val[14];
    {
        const float* src = v + g_ni * PQ + g_p0 * Hn + s;
        #pragma unroll
        for (int j = 0; j < 14; ++j) val[j] = src[j * Hn];   // imm-offset folded
    }

    // ---- phase B: sHt[c][p] = bf16( Σ_q gelu(arg) ) via Euler–Maclaurin:
    //   Σ_q gelu(u+v_q) = 28·g(m) + c2·W²·g''(m) + c4·W⁴·g⁗(m),  m = u+W/2
    {
        const int c = t & 63;
        const int pg = t >> 6;               // 4 groups x 7 p
        const float w0 = W1[c];
        const float Wc = W1[64 + c];         // w1[c] (signed)
        const float w2 = W1[128 + c];
        const float w3 = W1[192 + c];
        const float inv = 1.0f / 28.0f;
        const float base = ((r + 0.5f) * inv) * w2 + ((s + 0.5f) * inv) * w3
                         + b1[c] + 0.5f * Wc;
        const float w0i = inv * w0;
        const float W2c = Wc * Wc;
        const float c2 = 1.1651786f * W2c;            // 1827/(2*784)
        const float c4 = 0.0145213f * (W2c * W2c);    // 214215.75/(614656*24)
        #pragma unroll
        for (int pi = 0; pi < 7; ++pi) {
            const int p = pg * 7 + pi;
            const float m  = fmaf((float)p + 0.5f, w0i, base);
            const float m2 = m * m;
            const float E  = __builtin_amdgcn_exp2f(m2 * -0.72134752f);  // e^{-m²/2}
            const float az = fabsf(m) * 0.70710678f;
            const float tt = __builtin_amdgcn_rcpf(fmaf(0.3275911f, az, 1.0f));
            float poly = fmaf(tt, 1.061405429f, -1.453152027f);
            poly = fmaf(tt, poly, 1.421413741f);
            poly = fmaf(tt, poly, -0.284496736f);
            poly = fmaf(tt, poly, 0.254829592f);
            poly = poly * tt;
            float erfv = fmaf(-poly, E, 1.0f);
            erfv = (m < 0.0f) ? -erfv : erfv;
            const float g   = 0.5f * m * (1.0f + erfv);
            const float phi = 0.39894228f * E;
            const float p4  = fmaf(-m2, m2, fmaf(7.0f, m2, -4.0f));  // −m⁴+7m²−4
            const float corr = phi * fmaf(c4, p4, c2 * (2.0f - m2));
            sHt[c * 40 + p] = f2bf(fmaf(28.0f, g, corr));
        }
        if (pg == 3) *(uint2*)&sHt[c * 40 + 28] = make_uint2(0u, 0u);
    }

    // ---- finish stage V: fp32 row sums (replaces Vsum) + bf16 into sV
    {
        float vs = 0.0f;
        #pragma unroll
        for (int j = 0; j < 14; ++j) {
            vs += val[j];
            sV[g_ni * 40 + g_p0 + j] = f2bf(val[j]);
        }
        if (t & 1) *(uint2*)&sV[g_ni * 40 + 28] = make_uint2(0u, 0u);  // zero pad p=28..31
        vs += __shfl_xor(vs, 1);
        if (!(t & 1)) sVs[g_ni] = vs;
    }
    __syncthreads();

    // ---- phase D (MFMA): T[ni][c] = sum_p V[ni][p] * H[p][c]
    const int w  = t >> 6;          // wave 0..3
    const int l  = t & 63;
    const int lm = l & 15;
    const int q  = l >> 4;
    const int k0 = q * 8;

    {
        short8v aF[2], bF[4];
        aF[0] = *(const short8v*)&sV[(32 * w + lm) * 40 + k0];
        aF[1] = *(const short8v*)&sV[(32 * w + 16 + lm) * 40 + k0];
        #pragma unroll
        for (int nt = 0; nt < 4; ++nt)
            bF[nt] = *(const short8v*)&sHt[(16 * nt + lm) * 40 + k0];

        float4v accD[2][4];
        #pragma unroll
        for (int mt = 0; mt < 2; ++mt)
            #pragma unroll
            for (int nt = 0; nt < 4; ++nt)
                accD[mt][nt] = __builtin_amdgcn_mfma_f32_16x16x32_bf16(
                    aF[mt], bF[nt], (float4v)(0.0f), 0, 0, 0);

        // pack T to sTa[n8][c*16+i]: ni = 32w+16mt+4q+reg -> n8=2w+mt, i=4q+reg.
        #pragma unroll
        for (int mt = 0; mt < 2; ++mt) {
            const int n8 = 2 * w + mt;
            #pragma unroll
            for (int nt = 0; nt < 4; ++nt) {
                const int c = 16 * nt + lm;
                short4v pk;
                pk[0] = f2bf(accD[mt][nt][0]);
                pk[1] = f2bf(accD[mt][nt][1]);
                pk[2] = f2bf(accD[mt][nt][2]);
                pk[3] = f2bf(accD[mt][nt][3]);
                *(short4v*)&sTa[n8 * 1032 + c * 16 + 4 * q] = pk;
            }
        }
    }
    __syncthreads();

    // ---- phase D2 (MFMA): out[n8][o] = sum_k Ta[n8][k] * bf16(W2)[k][o],
    // K=1024 split over waves; W2 converted fp32->bf16 on the fly (bit-identical
    // to the old precomputed W2b, saves the prep kernel + workspace round-trip).
    float4v accO = (float4v)(0.0f);
    #pragma unroll
    for (int st = 0; st < 8; ++st) {
        const int kb = w * 256 + st * 32 + k0;
        const short8v a = *(const short8v*)&sTa[(lm & 7) * 1032 + kb];  // rows m>=8: dup, unused
        const int c  = kb >> 4;
        const int i0 = kb & 15;                                        // 0 or 8
        const float* wp = W2 + c * 256 + lm * 16 + i0;                 // 16-B aligned
        const float4 f0 = *(const float4*)(wp);
        const float4 f1 = *(const float4*)(wp + 4);
        short8v bfr;
        bfr[0] = f2bf(f0.x); bfr[1] = f2bf(f0.y);
        bfr[2] = f2bf(f0.z); bfr[3] = f2bf(f0.w);
        bfr[4] = f2bf(f1.x); bfr[5] = f2bf(f1.y);
        bfr[6] = f2bf(f1.z); bfr[7] = f2bf(f1.w);
        accO = __builtin_amdgcn_mfma_f32_16x16x32_bf16(a, bfr, accO, 0, 0, 0);
    }
    #pragma unroll
    for (int reg = 0; reg < 4; ++reg) {
        const int m = q * 4 + reg;                 // 0..15, valid m<8
        sRed[w * 256 + m * 16 + lm] = accO[reg];
    }
    __syncthreads();

    // ---- E: reduce 4 wave-partials, add b2 term + bias, store
    if (t < NI) {
        const int n8 = t >> 4;
        const int o  = t & 15;
        const int e  = n8 * 16 + o;
        const float tot = sRed[e] + sRed[256 + e] + sRed[512 + e] + sRed[768 + e];
        float bsum = 0.0f;
        #pragma unroll
        for (int i = 0; i < 16; ++i)
            bsum = fmaf(b2[o * 16 + i], sVs[n8 * 16 + i], bsum);
        out[(n8 * 16 + o) * PQ + rs] = (tot + 28.0f * bsum) * (1.0f / 784.0f) + bias[o];
    }
}

extern "C" void kernel_launch(void* const* d_in, const int* in_sizes, int n_in,
                              void* d_out, int out_size, void* d_ws, size_t ws_size,
                              hipStream_t stream) {
    const float* v    = (const float*)d_in[0];  // (8,16,28,28)
    const float* W1   = (const float*)d_in[1];  // (4,64)
    const float* b1   = (const float*)d_in[2];  // (64,)
    const float* W2   = (const float*)d_in[3];  // (64,256)
    const float* b2   = (const float*)d_in[4];  // (256,)
    const float* bias = (const float*)d_in[5];  // (16,1,1)
    float* out = (float*)d_out;                 // (8,16,28,28) fp32

    (void)d_ws; (void)ws_size;                  // no workspace: single dispatch
    mono_kernel<<<PQ, 256, 0, stream>>>(v, W1, b1, W2, b2, bias, out);
}